// Round 1
// baseline (2563.173 us; speedup 1.0000x reference)
//
#include <hip/hip_runtime.h>

#define NROWS 131072
#define KE 2048

typedef unsigned long long u64_t;

__device__ __forceinline__ unsigned f32_key(float f) {
  unsigned u = __float_as_uint(f);
  return (u & 0x80000000u) ? ~u : (u | 0x80000000u);
}

// Tiled f32 GEMM: BM=BN=64, BK=16, 256 threads, 4x4 per thread.
// MODE 0: C = relu(A@B + bias)                (A: MxK row-major, B: KxN row-major)
// MODE 1: same, but A row r is A[gidx[r]]     (gathered rows, A has KE rows)
// MODE 2: recon loss: v=relu(acc+bias); d=v-X[row,col]; block-sum -> parts (no C write)
// MODE 3: distance+argmin: B is [N x K] row-major (emb);
//         score = (zsq[row] - 2*p) + esq[col]; packed u64 atomicMin into keys.
template <int MODE>
__global__ __launch_bounds__(256) void gemm64(
    const float* __restrict__ A, const float* __restrict__ B,
    const float* __restrict__ bias, float* __restrict__ C,
    int M, int N, int K,
    const int* __restrict__ gidx,
    const float* __restrict__ X,
    float* __restrict__ parts,
    const float* __restrict__ zsq,
    const float* __restrict__ esq,
    u64_t* __restrict__ keys) {
  __shared__ __align__(16) float As[16][68];
  __shared__ __align__(16) float Bs[16][68];

  const int tid = threadIdx.x;
  const int tx = tid & 15;
  const int ty = tid >> 4;
  const int arow = blockIdx.x * 64;
  const int bcol = blockIdx.y * 64;

  // A tile load mapping: thread -> (row lr, 4 cols at lc)
  const int lr = tid >> 2;
  const int lc = (tid & 3) * 4;
  int ga = arow + lr;
  if (MODE == 1) ga = gidx[ga];
  const float* Ap = A + (size_t)ga * K + lc;

  // B tile load mapping
  const int bkr = tid >> 4;        // non-BT: k row 0..15
  const int bc4 = (tid & 15) * 4;  // non-BT: col offset
  const float* Bp;
  if (MODE == 3) {
    Bp = B + (size_t)(bcol + lr) * K + lc;  // emb rows, contraction contiguous
  } else {
    Bp = B + (size_t)bkr * N + bcol + bc4;
  }

  float acc[4][4] = {};

  for (int kt = 0; kt < K; kt += 16) {
    float4 av = *reinterpret_cast<const float4*>(Ap);
    As[lc + 0][lr] = av.x;
    As[lc + 1][lr] = av.y;
    As[lc + 2][lr] = av.z;
    As[lc + 3][lr] = av.w;
    if (MODE == 3) {
      float4 bv = *reinterpret_cast<const float4*>(Bp);
      Bs[lc + 0][lr] = bv.x;
      Bs[lc + 1][lr] = bv.y;
      Bs[lc + 2][lr] = bv.z;
      Bs[lc + 3][lr] = bv.w;
      Bp += 16;
    } else {
      float4 bv = *reinterpret_cast<const float4*>(Bp);
      *reinterpret_cast<float4*>(&Bs[bkr][bc4]) = bv;
      Bp += (size_t)16 * N;
    }
    Ap += 16;
    __syncthreads();
#pragma unroll
    for (int k = 0; k < 16; ++k) {
      float4 a = *reinterpret_cast<const float4*>(&As[k][ty * 4]);
      float4 b = *reinterpret_cast<const float4*>(&Bs[k][tx * 4]);
      acc[0][0] += a.x * b.x; acc[0][1] += a.x * b.y; acc[0][2] += a.x * b.z; acc[0][3] += a.x * b.w;
      acc[1][0] += a.y * b.x; acc[1][1] += a.y * b.y; acc[1][2] += a.y * b.z; acc[1][3] += a.y * b.w;
      acc[2][0] += a.z * b.x; acc[2][1] += a.z * b.y; acc[2][2] += a.z * b.z; acc[2][3] += a.z * b.w;
      acc[3][0] += a.w * b.x; acc[3][1] += a.w * b.y; acc[3][2] += a.w * b.z; acc[3][3] += a.w * b.w;
    }
    __syncthreads();
  }

  if (MODE == 0 || MODE == 1) {
#pragma unroll
    for (int i = 0; i < 4; ++i) {
      const int row = arow + ty * 4 + i;
      float4 v;
      v.x = fmaxf(acc[i][0] + bias[bcol + tx * 4 + 0], 0.f);
      v.y = fmaxf(acc[i][1] + bias[bcol + tx * 4 + 1], 0.f);
      v.z = fmaxf(acc[i][2] + bias[bcol + tx * 4 + 2], 0.f);
      v.w = fmaxf(acc[i][3] + bias[bcol + tx * 4 + 3], 0.f);
      *reinterpret_cast<float4*>(&C[(size_t)row * N + bcol + tx * 4]) = v;
    }
  } else if (MODE == 2) {
    float local = 0.f;
#pragma unroll
    for (int i = 0; i < 4; ++i) {
      const int row = arow + ty * 4 + i;
#pragma unroll
      for (int j = 0; j < 4; ++j) {
        const int col = bcol + tx * 4 + j;
        float v = fmaxf(acc[i][j] + bias[col], 0.f);
        float d = v - X[(size_t)row * N + col];
        local += d * d;
      }
    }
    __shared__ float rbuf[256];
    rbuf[tid] = local;
    __syncthreads();
    for (int off = 128; off > 0; off >>= 1) {
      if (tid < off) rbuf[tid] += rbuf[tid + off];
      __syncthreads();
    }
    if (tid == 0) parts[blockIdx.y * gridDim.x + blockIdx.x] = rbuf[0];
  } else if (MODE == 3) {
    __shared__ u64_t mb[64][16];
#pragma unroll
    for (int i = 0; i < 4; ++i) {
      const int row = ty * 4 + i;
      const float zs = zsq[arow + row];
      u64_t best = ~0ull;
#pragma unroll
      for (int j = 0; j < 4; ++j) {
        const int col = bcol + tx * 4 + j;
        // exact reference rounding: (z_sq - 2*p) + e_sq   (2*p is exact in fp)
        float dsc = (zs - 2.0f * acc[i][j]) + esq[col];
        u64_t kk = ((u64_t)f32_key(dsc) << 32) | (unsigned)col;
        if (kk < best) best = kk;
      }
      mb[row][tx] = best;
    }
    __syncthreads();
    if (tid < 64) {
      u64_t b = mb[tid][0];
#pragma unroll
      for (int t = 1; t < 16; ++t) {
        u64_t v = mb[tid][t];
        if (v < b) b = v;
      }
      atomicMin(&keys[arow + tid], b);
    }
  }
}

// sum of squares per row (256 cols); block = 4 rows x 64 lanes
__global__ __launch_bounds__(256) void rowsq(const float* __restrict__ src,
                                             float* __restrict__ dst, int rows) {
  const int sub = threadIdx.x >> 6;
  const int lane = threadIdx.x & 63;
  const int r = blockIdx.x * 4 + sub;
  if (r >= rows) return;
  const float* p = src + (size_t)r * 256;
  float s = 0.f;
#pragma unroll
  for (int j = 0; j < 4; ++j) {
    float v = p[lane + 64 * j];
    s += v * v;
  }
#pragma unroll
  for (int off = 32; off > 0; off >>= 1) s += __shfl_down(s, off, 64);
  if (lane == 0) dst[r] = s;
}

__global__ __launch_bounds__(256) void init_keys(u64_t* __restrict__ keys) {
  keys[(size_t)blockIdx.x * 256 + threadIdx.x] = ~0ull;
}

// per row: idx from key, write z_latent = z + (e - z), quant-loss partial sums
__global__ __launch_bounds__(256) void gather_quant(
    const u64_t* __restrict__ keys, const float* __restrict__ emb,
    const float* __restrict__ z_e, float* __restrict__ zlat,
    int* __restrict__ idx_out, float* __restrict__ qparts) {
  const int sub = threadIdx.x >> 6;
  const int lane = threadIdx.x & 63;
  const int r = blockIdx.x * 4 + sub;
  const int idx = (int)(keys[r] & 0xFFFFFFFFull);
  if (lane == 0) idx_out[r] = idx;
  float s = 0.f;
#pragma unroll
  for (int j = 0; j < 4; ++j) {
    const int d = lane + 64 * j;
    float e = emb[(size_t)idx * 256 + d];
    float z = z_e[(size_t)r * 256 + d];
    float df = e - z;           // fl(z_q - z_e)
    s += df * df;               // quant loss term
    zlat[(size_t)r * 256 + d] = z + df;  // fl(z_e + fl(z_q - z_e)) - exact ref order
  }
#pragma unroll
  for (int off = 32; off > 0; off >>= 1) s += __shfl_down(s, off, 64);
  __shared__ float red[4];
  if (lane == 0) red[sub] = s;
  __syncthreads();
  if (threadIdx.x == 0) qparts[blockIdx.x] = (red[0] + red[1]) + (red[2] + red[3]);
}

__global__ __launch_bounds__(256) void final_loss(
    const float* __restrict__ qparts, int nq,
    const float* __restrict__ rparts, int nr, float* __restrict__ out) {
  const int tid = threadIdx.x;
  double sq = 0.0, sr = 0.0;
  for (int i = tid; i < nq; i += 256) sq += (double)qparts[i];
  for (int i = tid; i < nr; i += 256) sr += (double)rparts[i];
  __shared__ double bq[256], br[256];
  bq[tid] = sq;
  br[tid] = sr;
  __syncthreads();
  for (int off = 128; off > 0; off >>= 1) {
    if (tid < off) {
      bq[tid] += bq[tid + off];
      br[tid] += br[tid + off];
    }
    __syncthreads();
  }
  if (tid == 0) {
    double qm = bq[0] / ((double)NROWS * 256.0);
    double rm = br[0] / ((double)NROWS * 512.0);
    out[(size_t)NROWS * 256] = (float)(rm + 1.25 * qm);  // recon + (1+BETA)*quant
  }
}

extern "C" void kernel_launch(void* const* d_in, const int* in_sizes, int n_in,
                              void* d_out, int out_size, void* d_ws, size_t ws_size,
                              hipStream_t stream) {
  const float* x   = (const float*)d_in[0];
  const float* ew1 = (const float*)d_in[1];
  const float* eb1 = (const float*)d_in[2];
  const float* ew2 = (const float*)d_in[3];
  const float* eb2 = (const float*)d_in[4];
  const float* ew3 = (const float*)d_in[5];
  const float* eb3 = (const float*)d_in[6];
  const float* dw1 = (const float*)d_in[7];
  const float* db1 = (const float*)d_in[8];
  const float* dw2 = (const float*)d_in[9];
  const float* db2 = (const float*)d_in[10];
  const float* dw3 = (const float*)d_in[11];
  const float* db3 = (const float*)d_in[12];
  const float* emb = (const float*)d_in[13];

  char* ws = (char*)d_ws;
  float* h1     = (float*)(ws);                    // N x 64   (later reused as dh2)
  float* h2     = (float*)(ws + 33554432ull);      // N x 128  (later reused as dh1)
  float* z_e    = (float*)(ws + 100663296ull);     // N x 256
  float* zsq    = (float*)(ws + 234881024ull);     // N
  float* esq    = (float*)(ws + 235405312ull);     // KE
  u64_t* keys   = (u64_t*)(ws + 235413504ull);     // N
  int* idx      = (int*)(ws + 236462080ull);       // N
  float* qparts = (float*)(ws + 236986368ull);     // N/4 = 32768
  float* rparts = (float*)(ws + 237117440ull);     // 2048*8 = 16384

  float* out = (float*)d_out;

  dim3 blk(256);

  // encoder: 512 -> 64 -> 128 -> 256 (relu each)
  gemm64<0><<<dim3(NROWS / 64, 1), blk, 0, stream>>>(x, ew1, eb1, h1, NROWS, 64, 512,
      nullptr, nullptr, nullptr, nullptr, nullptr, nullptr);
  gemm64<0><<<dim3(NROWS / 64, 2), blk, 0, stream>>>(h1, ew2, eb2, h2, NROWS, 128, 64,
      nullptr, nullptr, nullptr, nullptr, nullptr, nullptr);
  gemm64<0><<<dim3(NROWS / 64, 4), blk, 0, stream>>>(h2, ew3, eb3, z_e, NROWS, 256, 128,
      nullptr, nullptr, nullptr, nullptr, nullptr, nullptr);

  // per-row / per-embedding squared norms
  rowsq<<<dim3(NROWS / 4), blk, 0, stream>>>(z_e, zsq, NROWS);
  rowsq<<<dim3(KE / 4), blk, 0, stream>>>(emb, esq, KE);
  init_keys<<<dim3(NROWS / 256), blk, 0, stream>>>(keys);

  // distances + argmin (fused, no NxK materialization)
  gemm64<3><<<dim3(NROWS / 64, KE / 64), blk, 0, stream>>>(z_e, emb, nullptr, nullptr,
      NROWS, KE, 256, nullptr, nullptr, nullptr, zsq, esq, keys);

  // gather z_q, write z_latent, quant-loss partials
  gather_quant<<<dim3(NROWS / 4), blk, 0, stream>>>(keys, emb, z_e, out, idx, qparts);

  // decoder: 256 -> 128 -> 64 -> 512 (relu each); layer1 gathers emb rows via idx
  gemm64<1><<<dim3(NROWS / 64, 2), blk, 0, stream>>>(emb, dw1, db1, h2, NROWS, 128, 256,
      idx, nullptr, nullptr, nullptr, nullptr, nullptr);
  gemm64<0><<<dim3(NROWS / 64, 1), blk, 0, stream>>>(h2, dw2, db2, h1, NROWS, 64, 128,
      nullptr, nullptr, nullptr, nullptr, nullptr, nullptr);
  // layer3 fused with recon-loss partial sums (x_recon never materialized)
  gemm64<2><<<dim3(NROWS / 64, 8), blk, 0, stream>>>(h1, dw3, db3, nullptr, NROWS, 512, 64,
      nullptr, x, rparts, nullptr, nullptr, nullptr);

  final_loss<<<dim3(1), blk, 0, stream>>>(qparts, NROWS / 4, rparts, 16384, out);
}

// Round 2
// 2256.539 us; speedup vs baseline: 1.1359x; 1.1359x over previous
//
#include <hip/hip_runtime.h>

#define NROWS 131072
#define KE 2048

typedef unsigned long long u64_t;

__device__ __forceinline__ unsigned f32_key(float f) {
  unsigned u = __float_as_uint(f);
  return (u & 0x80000000u) ? ~u : (u | 0x80000000u);
}

// ---------------------------------------------------------------------------
// 64x64 tile f32 GEMM (UNCHANGED from round 1 — keeps z_e bit-identical).
// Used for: encoder L1/L2/L3, decoder L2.  MODE 0 only is instantiated.
// ---------------------------------------------------------------------------
template <int MODE>
__global__ __launch_bounds__(256) void gemm64(
    const float* __restrict__ A, const float* __restrict__ B,
    const float* __restrict__ bias, float* __restrict__ C,
    int M, int N, int K,
    const int* __restrict__ gidx,
    const float* __restrict__ X,
    float* __restrict__ parts,
    const float* __restrict__ zsq,
    const float* __restrict__ esq,
    u64_t* __restrict__ keys) {
  __shared__ __align__(16) float As[16][68];
  __shared__ __align__(16) float Bs[16][68];

  const int tid = threadIdx.x;
  const int tx = tid & 15;
  const int ty = tid >> 4;
  const int arow = blockIdx.x * 64;
  const int bcol = blockIdx.y * 64;

  const int lr = tid >> 2;
  const int lc = (tid & 3) * 4;
  int ga = arow + lr;
  if (MODE == 1) ga = gidx[ga];
  const float* Ap = A + (size_t)ga * K + lc;

  const int bkr = tid >> 4;
  const int bc4 = (tid & 15) * 4;
  const float* Bp;
  if (MODE == 3) {
    Bp = B + (size_t)(bcol + lr) * K + lc;
  } else {
    Bp = B + (size_t)bkr * N + bcol + bc4;
  }

  float acc[4][4] = {};

  for (int kt = 0; kt < K; kt += 16) {
    float4 av = *reinterpret_cast<const float4*>(Ap);
    As[lc + 0][lr] = av.x;
    As[lc + 1][lr] = av.y;
    As[lc + 2][lr] = av.z;
    As[lc + 3][lr] = av.w;
    if (MODE == 3) {
      float4 bv = *reinterpret_cast<const float4*>(Bp);
      Bs[lc + 0][lr] = bv.x;
      Bs[lc + 1][lr] = bv.y;
      Bs[lc + 2][lr] = bv.z;
      Bs[lc + 3][lr] = bv.w;
      Bp += 16;
    } else {
      float4 bv = *reinterpret_cast<const float4*>(Bp);
      *reinterpret_cast<float4*>(&Bs[bkr][bc4]) = bv;
      Bp += (size_t)16 * N;
    }
    Ap += 16;
    __syncthreads();
#pragma unroll
    for (int k = 0; k < 16; ++k) {
      float4 a = *reinterpret_cast<const float4*>(&As[k][ty * 4]);
      float4 b = *reinterpret_cast<const float4*>(&Bs[k][tx * 4]);
      acc[0][0] += a.x * b.x; acc[0][1] += a.x * b.y; acc[0][2] += a.x * b.z; acc[0][3] += a.x * b.w;
      acc[1][0] += a.y * b.x; acc[1][1] += a.y * b.y; acc[1][2] += a.y * b.z; acc[1][3] += a.y * b.w;
      acc[2][0] += a.z * b.x; acc[2][1] += a.z * b.y; acc[2][2] += a.z * b.z; acc[2][3] += a.z * b.w;
      acc[3][0] += a.w * b.x; acc[3][1] += a.w * b.y; acc[3][2] += a.w * b.z; acc[3][3] += a.w * b.w;
    }
    __syncthreads();
  }

  if (MODE == 0 || MODE == 1) {
#pragma unroll
    for (int i = 0; i < 4; ++i) {
      const int row = arow + ty * 4 + i;
      float4 v;
      v.x = fmaxf(acc[i][0] + bias[bcol + tx * 4 + 0], 0.f);
      v.y = fmaxf(acc[i][1] + bias[bcol + tx * 4 + 1], 0.f);
      v.z = fmaxf(acc[i][2] + bias[bcol + tx * 4 + 2], 0.f);
      v.w = fmaxf(acc[i][3] + bias[bcol + tx * 4 + 3], 0.f);
      *reinterpret_cast<float4*>(&C[(size_t)row * N + bcol + tx * 4]) = v;
    }
  }
}

// ---------------------------------------------------------------------------
// 128x128 tile f32 GEMM, BK=16, 256 threads, 8x8 per thread (~105 VGPR).
// Accumulation per output element is strictly sequential over k (ascending),
// so MODE 3 produces bit-identical dot products to the round-1 kernel.
// MODE 1: C = relu(A[gidx[row]] @ B + bias)       (dec L1)
// MODE 2: recon-loss partial sums, no C write      (dec L3)
// MODE 3: distance scores + argmin via atomicMin   (distance GEMM)
// ---------------------------------------------------------------------------
template <int MODE>
__global__ __launch_bounds__(256) void gemm128(
    const float* __restrict__ A, const float* __restrict__ B,
    const float* __restrict__ bias, float* __restrict__ C,
    int N, int K,
    const int* __restrict__ gidx,
    const float* __restrict__ X,
    float* __restrict__ parts,
    const float* __restrict__ zsq,
    const float* __restrict__ esq,
    u64_t* __restrict__ keys) {
  // As[16][132] (8448 B) + Bs[16][132] (8448 B); MODE3 reuses as mb[128][17]
  __shared__ __align__(16) char smem[17408];
  float (*As)[132] = (float(*)[132])smem;
  float (*Bs)[132] = (float(*)[132])(smem + 8448);

  const int tid = threadIdx.x;
  const int tx = tid & 15;
  const int ty = tid >> 4;
  const int arow = blockIdx.x * 128;
  const int bcol = blockIdx.y * 128;

  // A staging: two float4/thread, transposed scatter into As[k][row]
  const int r0 = tid >> 2;        // 0..63
  const int r1 = r0 + 64;         // 64..127
  const int lc = (tid & 3) * 4;   // 0,4,8,12
  int ga0 = arow + r0, ga1 = arow + r1;
  if (MODE == 1) { ga0 = gidx[ga0]; ga1 = gidx[ga1]; }
  const float* Ap0 = A + (size_t)ga0 * K + lc;
  const float* Ap1 = A + (size_t)ga1 * K + lc;

  // B staging
  const float* Bp0;
  const float* Bp1;
  int bk0 = 0, bc0 = 0;
  if (MODE == 3) {
    Bp0 = B + (size_t)(bcol + r0) * K + lc;   // emb rows, contraction contiguous
    Bp1 = B + (size_t)(bcol + r1) * K + lc;
  } else {
    bk0 = tid >> 5;                 // 0..7
    bc0 = (tid & 31) * 4;           // 0..124
    Bp0 = B + (size_t)bk0 * N + bcol + bc0;
    Bp1 = B + (size_t)(bk0 + 8) * N + bcol + bc0;
  }

  float acc[8][8] = {};

  for (int kt = 0; kt < K; kt += 16) {
    float4 a0 = *reinterpret_cast<const float4*>(Ap0);
    float4 a1 = *reinterpret_cast<const float4*>(Ap1);
    As[lc + 0][r0] = a0.x; As[lc + 1][r0] = a0.y; As[lc + 2][r0] = a0.z; As[lc + 3][r0] = a0.w;
    As[lc + 0][r1] = a1.x; As[lc + 1][r1] = a1.y; As[lc + 2][r1] = a1.z; As[lc + 3][r1] = a1.w;
    if (MODE == 3) {
      float4 b0 = *reinterpret_cast<const float4*>(Bp0);
      float4 b1 = *reinterpret_cast<const float4*>(Bp1);
      Bs[lc + 0][r0] = b0.x; Bs[lc + 1][r0] = b0.y; Bs[lc + 2][r0] = b0.z; Bs[lc + 3][r0] = b0.w;
      Bs[lc + 0][r1] = b1.x; Bs[lc + 1][r1] = b1.y; Bs[lc + 2][r1] = b1.z; Bs[lc + 3][r1] = b1.w;
      Bp0 += 16; Bp1 += 16;
    } else {
      float4 b0 = *reinterpret_cast<const float4*>(Bp0);
      float4 b1 = *reinterpret_cast<const float4*>(Bp1);
      *reinterpret_cast<float4*>(&Bs[bk0][bc0]) = b0;
      *reinterpret_cast<float4*>(&Bs[bk0 + 8][bc0]) = b1;
      Bp0 += (size_t)16 * N; Bp1 += (size_t)16 * N;
    }
    Ap0 += 16; Ap1 += 16;
    __syncthreads();
#pragma unroll
    for (int k = 0; k < 16; ++k) {
      float4 av0 = *reinterpret_cast<const float4*>(&As[k][ty * 8]);
      float4 av1 = *reinterpret_cast<const float4*>(&As[k][ty * 8 + 4]);
      float4 bv0 = *reinterpret_cast<const float4*>(&Bs[k][tx * 8]);
      float4 bv1 = *reinterpret_cast<const float4*>(&Bs[k][tx * 8 + 4]);
      const float a[8] = {av0.x, av0.y, av0.z, av0.w, av1.x, av1.y, av1.z, av1.w};
      const float b[8] = {bv0.x, bv0.y, bv0.z, bv0.w, bv1.x, bv1.y, bv1.z, bv1.w};
#pragma unroll
      for (int i = 0; i < 8; ++i)
#pragma unroll
        for (int j = 0; j < 8; ++j) acc[i][j] += a[i] * b[j];
    }
    __syncthreads();  // also protects smem reuse in the epilogues below
  }

  if (MODE == 1) {
#pragma unroll
    for (int i = 0; i < 8; ++i) {
      const int row = arow + ty * 8 + i;
      float4 v0, v1;
      v0.x = fmaxf(acc[i][0] + bias[bcol + tx * 8 + 0], 0.f);
      v0.y = fmaxf(acc[i][1] + bias[bcol + tx * 8 + 1], 0.f);
      v0.z = fmaxf(acc[i][2] + bias[bcol + tx * 8 + 2], 0.f);
      v0.w = fmaxf(acc[i][3] + bias[bcol + tx * 8 + 3], 0.f);
      v1.x = fmaxf(acc[i][4] + bias[bcol + tx * 8 + 4], 0.f);
      v1.y = fmaxf(acc[i][5] + bias[bcol + tx * 8 + 5], 0.f);
      v1.z = fmaxf(acc[i][6] + bias[bcol + tx * 8 + 6], 0.f);
      v1.w = fmaxf(acc[i][7] + bias[bcol + tx * 8 + 7], 0.f);
      *reinterpret_cast<float4*>(&C[(size_t)row * N + bcol + tx * 8]) = v0;
      *reinterpret_cast<float4*>(&C[(size_t)row * N + bcol + tx * 8 + 4]) = v1;
    }
  } else if (MODE == 2) {
    float local = 0.f;
#pragma unroll
    for (int i = 0; i < 8; ++i) {
      const int row = arow + ty * 8 + i;
#pragma unroll
      for (int j = 0; j < 8; ++j) {
        const int col = bcol + tx * 8 + j;
        float v = fmaxf(acc[i][j] + bias[col], 0.f);
        float d = v - X[(size_t)row * N + col];
        local += d * d;
      }
    }
    float* rbuf = (float*)smem;  // safe: post-loop barrier above
    rbuf[tid] = local;
    __syncthreads();
    for (int off = 128; off > 0; off >>= 1) {
      if (tid < off) rbuf[tid] += rbuf[tid + off];
      __syncthreads();
    }
    if (tid == 0) parts[blockIdx.y * gridDim.x + blockIdx.x] = rbuf[0];
  } else if (MODE == 3) {
    u64_t (*mb)[17] = (u64_t(*)[17])smem;  // 17408 B, safe: post-loop barrier
#pragma unroll
    for (int i = 0; i < 8; ++i) {
      const int row = ty * 8 + i;
      const float zs = zsq[arow + row];
      u64_t best = ~0ull;
#pragma unroll
      for (int j = 0; j < 8; ++j) {
        const int col = bcol + tx * 8 + j;
        // exact reference rounding: (z_sq - 2*p) + e_sq  (2*p exact in fp)
        float dsc = (zs - 2.0f * acc[i][j]) + esq[col];
        u64_t kk = ((u64_t)f32_key(dsc) << 32) | (unsigned)col;
        if (kk < best) best = kk;
      }
      mb[row][tx] = best;
    }
    __syncthreads();
    if (tid < 128) {
      u64_t b = mb[tid][0];
#pragma unroll
      for (int t = 1; t < 16; ++t) {
        u64_t v = mb[tid][t];
        if (v < b) b = v;
      }
      atomicMin(&keys[arow + tid], b);
    }
  }
}

// sum of squares per row (256 cols); block = 4 rows x 64 lanes
__global__ __launch_bounds__(256) void rowsq(const float* __restrict__ src,
                                             float* __restrict__ dst, int rows) {
  const int sub = threadIdx.x >> 6;
  const int lane = threadIdx.x & 63;
  const int r = blockIdx.x * 4 + sub;
  if (r >= rows) return;
  const float* p = src + (size_t)r * 256;
  float s = 0.f;
#pragma unroll
  for (int j = 0; j < 4; ++j) {
    float v = p[lane + 64 * j];
    s += v * v;
  }
#pragma unroll
  for (int off = 32; off > 0; off >>= 1) s += __shfl_down(s, off, 64);
  if (lane == 0) dst[r] = s;
}

__global__ __launch_bounds__(256) void init_keys(u64_t* __restrict__ keys) {
  keys[(size_t)blockIdx.x * 256 + threadIdx.x] = ~0ull;
}

// per row: idx from key, write z_latent = z + (e - z), quant-loss partial sums
__global__ __launch_bounds__(256) void gather_quant(
    const u64_t* __restrict__ keys, const float* __restrict__ emb,
    const float* __restrict__ z_e, float* __restrict__ zlat,
    int* __restrict__ idx_out, float* __restrict__ qparts) {
  const int sub = threadIdx.x >> 6;
  const int lane = threadIdx.x & 63;
  const int r = blockIdx.x * 4 + sub;
  const int idx = (int)(keys[r] & 0xFFFFFFFFull);
  if (lane == 0) idx_out[r] = idx;
  float s = 0.f;
#pragma unroll
  for (int j = 0; j < 4; ++j) {
    const int d = lane + 64 * j;
    float e = emb[(size_t)idx * 256 + d];
    float z = z_e[(size_t)r * 256 + d];
    float df = e - z;
    s += df * df;
    zlat[(size_t)r * 256 + d] = z + df;  // fl(z_e + fl(z_q - z_e)) — exact ref order
  }
#pragma unroll
  for (int off = 32; off > 0; off >>= 1) s += __shfl_down(s, off, 64);
  __shared__ float red[4];
  if (lane == 0) red[sub] = s;
  __syncthreads();
  if (threadIdx.x == 0) qparts[blockIdx.x] = (red[0] + red[1]) + (red[2] + red[3]);
}

__global__ __launch_bounds__(256) void final_loss(
    const float* __restrict__ qparts, int nq,
    const float* __restrict__ rparts, int nr, float* __restrict__ out) {
  const int tid = threadIdx.x;
  double sq = 0.0, sr = 0.0;
  for (int i = tid; i < nq; i += 256) sq += (double)qparts[i];
  for (int i = tid; i < nr; i += 256) sr += (double)rparts[i];
  __shared__ double bq[256], br[256];
  bq[tid] = sq;
  br[tid] = sr;
  __syncthreads();
  for (int off = 128; off > 0; off >>= 1) {
    if (tid < off) {
      bq[tid] += bq[tid + off];
      br[tid] += br[tid + off];
    }
    __syncthreads();
  }
  if (tid == 0) {
    double qm = bq[0] / ((double)NROWS * 256.0);
    double rm = br[0] / ((double)NROWS * 512.0);
    out[(size_t)NROWS * 256] = (float)(rm + 1.25 * qm);  // recon + (1+BETA)*quant
  }
}

extern "C" void kernel_launch(void* const* d_in, const int* in_sizes, int n_in,
                              void* d_out, int out_size, void* d_ws, size_t ws_size,
                              hipStream_t stream) {
  const float* x   = (const float*)d_in[0];
  const float* ew1 = (const float*)d_in[1];
  const float* eb1 = (const float*)d_in[2];
  const float* ew2 = (const float*)d_in[3];
  const float* eb2 = (const float*)d_in[4];
  const float* ew3 = (const float*)d_in[5];
  const float* eb3 = (const float*)d_in[6];
  const float* dw1 = (const float*)d_in[7];
  const float* db1 = (const float*)d_in[8];
  const float* dw2 = (const float*)d_in[9];
  const float* db2 = (const float*)d_in[10];
  const float* dw3 = (const float*)d_in[11];
  const float* db3 = (const float*)d_in[12];
  const float* emb = (const float*)d_in[13];

  char* ws = (char*)d_ws;
  float* h1     = (float*)(ws);                    // N x 64   (reused as dec h2)
  float* h2     = (float*)(ws + 33554432ull);      // N x 128  (reused as dec h1)
  float* z_e    = (float*)(ws + 100663296ull);     // N x 256
  float* zsq    = (float*)(ws + 234881024ull);     // N
  float* esq    = (float*)(ws + 235405312ull);     // KE
  u64_t* keys   = (u64_t*)(ws + 235413504ull);     // N
  int* idx      = (int*)(ws + 236462080ull);       // N
  float* qparts = (float*)(ws + 236986368ull);     // N/4 = 32768
  float* rparts = (float*)(ws + 237117440ull);     // 1024*4 = 4096

  float* out = (float*)d_out;

  dim3 blk(256);

  // encoder (UNCHANGED — z_e must stay bit-identical): 512 -> 64 -> 128 -> 256
  gemm64<0><<<dim3(NROWS / 64, 1), blk, 0, stream>>>(x, ew1, eb1, h1, NROWS, 64, 512,
      nullptr, nullptr, nullptr, nullptr, nullptr, nullptr);
  gemm64<0><<<dim3(NROWS / 64, 2), blk, 0, stream>>>(h1, ew2, eb2, h2, NROWS, 128, 64,
      nullptr, nullptr, nullptr, nullptr, nullptr, nullptr);
  gemm64<0><<<dim3(NROWS / 64, 4), blk, 0, stream>>>(h2, ew3, eb3, z_e, NROWS, 256, 128,
      nullptr, nullptr, nullptr, nullptr, nullptr, nullptr);

  rowsq<<<dim3(NROWS / 4), blk, 0, stream>>>(z_e, zsq, NROWS);
  rowsq<<<dim3(KE / 4), blk, 0, stream>>>(emb, esq, KE);
  init_keys<<<dim3(NROWS / 256), blk, 0, stream>>>(keys);

  // distances + argmin: 128x128 tile, bit-identical k-order dot products
  gemm128<3><<<dim3(NROWS / 128, KE / 128), blk, 0, stream>>>(z_e, emb, nullptr, nullptr,
      KE, 256, nullptr, nullptr, nullptr, zsq, esq, keys);

  gather_quant<<<dim3(NROWS / 4), blk, 0, stream>>>(keys, emb, z_e, out, idx, qparts);

  // decoder: 256 -> 128 -> 64 -> 512 (loss-only path, 2% threshold)
  gemm128<1><<<dim3(NROWS / 128, 1), blk, 0, stream>>>(emb, dw1, db1, h2,
      128, 256, idx, nullptr, nullptr, nullptr, nullptr, nullptr);
  gemm64<0><<<dim3(NROWS / 64, 1), blk, 0, stream>>>(h2, dw2, db2, h1, NROWS, 64, 128,
      nullptr, nullptr, nullptr, nullptr, nullptr, nullptr);
  gemm128<2><<<dim3(NROWS / 128, 4), blk, 0, stream>>>(h1, dw3, db3, nullptr,
      512, 64, nullptr, x, rparts, nullptr, nullptr, nullptr);

  final_loss<<<dim3(1), blk, 0, stream>>>(qparts, NROWS / 4, rparts, 4096, out);
}

// Round 3
// 2233.965 us; speedup vs baseline: 1.1474x; 1.0101x over previous
//
#include <hip/hip_runtime.h>

#define NROWS 131072
#define KE 2048

typedef unsigned long long u64_t;

__device__ __forceinline__ unsigned f32_key(float f) {
  unsigned u = __float_as_uint(f);
  return (u & 0x80000000u) ? ~u : (u | 0x80000000u);
}

// ---------------------------------------------------------------------------
// 64x64 tile f32 GEMM (UNCHANGED — keeps enc1/dec2 behavior). MODE 0 only.
// ---------------------------------------------------------------------------
template <int MODE>
__global__ __launch_bounds__(256) void gemm64(
    const float* __restrict__ A, const float* __restrict__ B,
    const float* __restrict__ bias, float* __restrict__ C,
    int M, int N, int K,
    const int* __restrict__ gidx) {
  __shared__ __align__(16) float As[16][68];
  __shared__ __align__(16) float Bs[16][68];

  const int tid = threadIdx.x;
  const int tx = tid & 15;
  const int ty = tid >> 4;
  const int arow = blockIdx.x * 64;
  const int bcol = blockIdx.y * 64;

  const int lr = tid >> 2;
  const int lc = (tid & 3) * 4;
  int ga = arow + lr;
  if (MODE == 1) ga = gidx[ga];
  const float* Ap = A + (size_t)ga * K + lc;

  const int bkr = tid >> 4;
  const int bc4 = (tid & 15) * 4;
  const float* Bp = B + (size_t)bkr * N + bcol + bc4;

  float acc[4][4] = {};

  for (int kt = 0; kt < K; kt += 16) {
    float4 av = *reinterpret_cast<const float4*>(Ap);
    As[lc + 0][lr] = av.x;
    As[lc + 1][lr] = av.y;
    As[lc + 2][lr] = av.z;
    As[lc + 3][lr] = av.w;
    float4 bv = *reinterpret_cast<const float4*>(Bp);
    *reinterpret_cast<float4*>(&Bs[bkr][bc4]) = bv;
    Bp += (size_t)16 * N;
    Ap += 16;
    __syncthreads();
#pragma unroll
    for (int k = 0; k < 16; ++k) {
      float4 a = *reinterpret_cast<const float4*>(&As[k][ty * 4]);
      float4 b = *reinterpret_cast<const float4*>(&Bs[k][tx * 4]);
      acc[0][0] += a.x * b.x; acc[0][1] += a.x * b.y; acc[0][2] += a.x * b.z; acc[0][3] += a.x * b.w;
      acc[1][0] += a.y * b.x; acc[1][1] += a.y * b.y; acc[1][2] += a.y * b.z; acc[1][3] += a.y * b.w;
      acc[2][0] += a.z * b.x; acc[2][1] += a.z * b.y; acc[2][2] += a.z * b.z; acc[2][3] += a.z * b.w;
      acc[3][0] += a.w * b.x; acc[3][1] += a.w * b.y; acc[3][2] += a.w * b.z; acc[3][3] += a.w * b.w;
    }
    __syncthreads();
  }

#pragma unroll
  for (int i = 0; i < 4; ++i) {
    const int row = arow + ty * 4 + i;
    float4 v;
    v.x = fmaxf(acc[i][0] + bias[bcol + tx * 4 + 0], 0.f);
    v.y = fmaxf(acc[i][1] + bias[bcol + tx * 4 + 1], 0.f);
    v.z = fmaxf(acc[i][2] + bias[bcol + tx * 4 + 2], 0.f);
    v.w = fmaxf(acc[i][3] + bias[bcol + tx * 4 + 3], 0.f);
    *reinterpret_cast<float4*>(&C[(size_t)row * N + bcol + tx * 4]) = v;
  }
}

// ---------------------------------------------------------------------------
// 128x128 tile f32 GEMM, BK=16, 256 threads, 8x8 per thread in 2x2 quadrants:
//   row(i) = (i>>2)*64 + ty*4 + (i&3),  col(j) = (j>>2)*64 + tx*4 + (j&3)
// Fragment ds_read_b128 at 16B stride -> <=2-way bank aliasing (free).
// Per-element accumulation is strictly sequential ascending-k fmac ->
// bit-identical dot products to rounds 1/2 (and to BLAS reference).
// MODE 0: C = relu(A@B + bias)
// MODE 1: C = relu(A[gidx[row]] @ B + bias)       (dec L1)
// MODE 2: recon-loss partial sums, no C write      (dec L3)
// MODE 3: distance scores + argmin via atomicMin   (distance GEMM)
// ---------------------------------------------------------------------------
template <int MODE>
__global__ __launch_bounds__(256) void gemm128(
    const float* __restrict__ A, const float* __restrict__ B,
    const float* __restrict__ bias, float* __restrict__ C,
    int N, int K,
    const int* __restrict__ gidx,
    const float* __restrict__ X,
    float* __restrict__ parts,
    const float* __restrict__ zsq,
    const float* __restrict__ esq,
    u64_t* __restrict__ keys) {
  __shared__ __align__(16) char smem[17408];
  float (*As)[132] = (float(*)[132])smem;
  float (*Bs)[132] = (float(*)[132])(smem + 8448);

  const int tid = threadIdx.x;
  const int tx = tid & 15;
  const int ty = tid >> 4;
  const int arow = blockIdx.x * 128;
  const int bcol = blockIdx.y * 128;

  // A staging: two float4/thread, transposed scatter into As[k][row]
  const int r0 = tid >> 2;        // 0..63
  const int r1 = r0 + 64;         // 64..127
  const int lc = (tid & 3) * 4;   // 0,4,8,12
  int ga0 = arow + r0, ga1 = arow + r1;
  if (MODE == 1) { ga0 = gidx[ga0]; ga1 = gidx[ga1]; }
  const float* Ap0 = A + (size_t)ga0 * K + lc;
  const float* Ap1 = A + (size_t)ga1 * K + lc;

  const float* Bp0;
  const float* Bp1;
  int bk0 = 0, bc0 = 0;
  if (MODE == 3) {
    Bp0 = B + (size_t)(bcol + r0) * K + lc;   // emb rows, contraction contiguous
    Bp1 = B + (size_t)(bcol + r1) * K + lc;
  } else {
    bk0 = tid >> 5;                 // 0..7
    bc0 = (tid & 31) * 4;           // 0..124
    Bp0 = B + (size_t)bk0 * N + bcol + bc0;
    Bp1 = B + (size_t)(bk0 + 8) * N + bcol + bc0;
  }

  float acc[8][8] = {};

  for (int kt = 0; kt < K; kt += 16) {
    float4 a0 = *reinterpret_cast<const float4*>(Ap0);
    float4 a1 = *reinterpret_cast<const float4*>(Ap1);
    As[lc + 0][r0] = a0.x; As[lc + 1][r0] = a0.y; As[lc + 2][r0] = a0.z; As[lc + 3][r0] = a0.w;
    As[lc + 0][r1] = a1.x; As[lc + 1][r1] = a1.y; As[lc + 2][r1] = a1.z; As[lc + 3][r1] = a1.w;
    if (MODE == 3) {
      float4 b0 = *reinterpret_cast<const float4*>(Bp0);
      float4 b1 = *reinterpret_cast<const float4*>(Bp1);
      Bs[lc + 0][r0] = b0.x; Bs[lc + 1][r0] = b0.y; Bs[lc + 2][r0] = b0.z; Bs[lc + 3][r0] = b0.w;
      Bs[lc + 0][r1] = b1.x; Bs[lc + 1][r1] = b1.y; Bs[lc + 2][r1] = b1.z; Bs[lc + 3][r1] = b1.w;
      Bp0 += 16; Bp1 += 16;
    } else {
      float4 b0 = *reinterpret_cast<const float4*>(Bp0);
      float4 b1 = *reinterpret_cast<const float4*>(Bp1);
      *reinterpret_cast<float4*>(&Bs[bk0][bc0]) = b0;
      *reinterpret_cast<float4*>(&Bs[bk0 + 8][bc0]) = b1;
      Bp0 += (size_t)16 * N; Bp1 += (size_t)16 * N;
    }
    Ap0 += 16; Ap1 += 16;
    __syncthreads();
#pragma unroll
    for (int k = 0; k < 16; ++k) {
      float4 av0 = *reinterpret_cast<const float4*>(&As[k][ty * 4]);
      float4 av1 = *reinterpret_cast<const float4*>(&As[k][64 + ty * 4]);
      float4 bv0 = *reinterpret_cast<const float4*>(&Bs[k][tx * 4]);
      float4 bv1 = *reinterpret_cast<const float4*>(&Bs[k][64 + tx * 4]);
      const float a[8] = {av0.x, av0.y, av0.z, av0.w, av1.x, av1.y, av1.z, av1.w};
      const float b[8] = {bv0.x, bv0.y, bv0.z, bv0.w, bv1.x, bv1.y, bv1.z, bv1.w};
#pragma unroll
      for (int i = 0; i < 8; ++i)
#pragma unroll
        for (int j = 0; j < 8; ++j) acc[i][j] += a[i] * b[j];
    }
    __syncthreads();  // also protects smem reuse in the epilogues below
  }

  if (MODE == 0 || MODE == 1) {
#pragma unroll
    for (int i = 0; i < 8; ++i) {
      const int row = arow + (i >> 2) * 64 + ty * 4 + (i & 3);
      const int c0 = bcol + tx * 4;
      const int c1 = bcol + 64 + tx * 4;
      float4 v0, v1;
      v0.x = fmaxf(acc[i][0] + bias[c0 + 0], 0.f);
      v0.y = fmaxf(acc[i][1] + bias[c0 + 1], 0.f);
      v0.z = fmaxf(acc[i][2] + bias[c0 + 2], 0.f);
      v0.w = fmaxf(acc[i][3] + bias[c0 + 3], 0.f);
      v1.x = fmaxf(acc[i][4] + bias[c1 + 0], 0.f);
      v1.y = fmaxf(acc[i][5] + bias[c1 + 1], 0.f);
      v1.z = fmaxf(acc[i][6] + bias[c1 + 2], 0.f);
      v1.w = fmaxf(acc[i][7] + bias[c1 + 3], 0.f);
      *reinterpret_cast<float4*>(&C[(size_t)row * N + c0]) = v0;
      *reinterpret_cast<float4*>(&C[(size_t)row * N + c1]) = v1;
    }
  } else if (MODE == 2) {
    float local = 0.f;
#pragma unroll
    for (int i = 0; i < 8; ++i) {
      const int row = arow + (i >> 2) * 64 + ty * 4 + (i & 3);
#pragma unroll
      for (int j = 0; j < 8; ++j) {
        const int col = bcol + (j >> 2) * 64 + tx * 4 + (j & 3);
        float v = fmaxf(acc[i][j] + bias[col], 0.f);
        float d = v - X[(size_t)row * N + col];
        local += d * d;
      }
    }
    float* rbuf = (float*)smem;  // safe: post-loop barrier above
    rbuf[tid] = local;
    __syncthreads();
    for (int off = 128; off > 0; off >>= 1) {
      if (tid < off) rbuf[tid] += rbuf[tid + off];
      __syncthreads();
    }
    if (tid == 0) parts[blockIdx.y * gridDim.x + blockIdx.x] = rbuf[0];
  } else if (MODE == 3) {
    u64_t (*mb)[17] = (u64_t(*)[17])smem;  // 17408 B, safe: post-loop barrier
#pragma unroll
    for (int i = 0; i < 8; ++i) {
      const int row = (i >> 2) * 64 + ty * 4 + (i & 3);
      const float zs = zsq[arow + row];
      u64_t best = ~0ull;
#pragma unroll
      for (int j = 0; j < 8; ++j) {
        const int col = bcol + (j >> 2) * 64 + tx * 4 + (j & 3);
        // exact reference rounding: (z_sq - 2*p) + e_sq  (2*p exact in fp)
        float dsc = (zs - 2.0f * acc[i][j]) + esq[col];
        u64_t kk = ((u64_t)f32_key(dsc) << 32) | (unsigned)col;
        if (kk < best) best = kk;
      }
      mb[row][tx] = best;
    }
    __syncthreads();
    if (tid < 128) {
      u64_t b = mb[tid][0];
#pragma unroll
      for (int t = 1; t < 16; ++t) {
        u64_t v = mb[tid][t];
        if (v < b) b = v;
      }
      atomicMin(&keys[arow + tid], b);
    }
  }
}

// sum of squares per row (256 cols); block = 4 rows x 64 lanes
__global__ __launch_bounds__(256) void rowsq(const float* __restrict__ src,
                                             float* __restrict__ dst, int rows) {
  const int sub = threadIdx.x >> 6;
  const int lane = threadIdx.x & 63;
  const int r = blockIdx.x * 4 + sub;
  if (r >= rows) return;
  const float* p = src + (size_t)r * 256;
  float s = 0.f;
#pragma unroll
  for (int j = 0; j < 4; ++j) {
    float v = p[lane + 64 * j];
    s += v * v;
  }
#pragma unroll
  for (int off = 32; off > 0; off >>= 1) s += __shfl_down(s, off, 64);
  if (lane == 0) dst[r] = s;
}

__global__ __launch_bounds__(256) void init_keys(u64_t* __restrict__ keys) {
  keys[(size_t)blockIdx.x * 256 + threadIdx.x] = ~0ull;
}

// per row: idx from key, write z_latent = z + (e - z), quant-loss partial sums
__global__ __launch_bounds__(256) void gather_quant(
    const u64_t* __restrict__ keys, const float* __restrict__ emb,
    const float* __restrict__ z_e, float* __restrict__ zlat,
    int* __restrict__ idx_out, float* __restrict__ qparts) {
  const int sub = threadIdx.x >> 6;
  const int lane = threadIdx.x & 63;
  const int r = blockIdx.x * 4 + sub;
  const int idx = (int)(keys[r] & 0xFFFFFFFFull);
  if (lane == 0) idx_out[r] = idx;
  float s = 0.f;
#pragma unroll
  for (int j = 0; j < 4; ++j) {
    const int d = lane + 64 * j;
    float e = emb[(size_t)idx * 256 + d];
    float z = z_e[(size_t)r * 256 + d];
    float df = e - z;
    s += df * df;
    zlat[(size_t)r * 256 + d] = z + df;  // fl(z_e + fl(z_q - z_e)) — exact ref order
  }
#pragma unroll
  for (int off = 32; off > 0; off >>= 1) s += __shfl_down(s, off, 64);
  __shared__ float red[4];
  if (lane == 0) red[sub] = s;
  __syncthreads();
  if (threadIdx.x == 0) qparts[blockIdx.x] = (red[0] + red[1]) + (red[2] + red[3]);
}

__global__ __launch_bounds__(256) void final_loss(
    const float* __restrict__ qparts, int nq,
    const float* __restrict__ rparts, int nr, float* __restrict__ out) {
  const int tid = threadIdx.x;
  double sq = 0.0, sr = 0.0;
  for (int i = tid; i < nq; i += 256) sq += (double)qparts[i];
  for (int i = tid; i < nr; i += 256) sr += (double)rparts[i];
  __shared__ double bq[256], br[256];
  bq[tid] = sq;
  br[tid] = sr;
  __syncthreads();
  for (int off = 128; off > 0; off >>= 1) {
    if (tid < off) {
      bq[tid] += bq[tid + off];
      br[tid] += br[tid + off];
    }
    __syncthreads();
  }
  if (tid == 0) {
    double qm = bq[0] / ((double)NROWS * 256.0);
    double rm = br[0] / ((double)NROWS * 512.0);
    out[(size_t)NROWS * 256] = (float)(rm + 1.25 * qm);  // recon + (1+BETA)*quant
  }
}

extern "C" void kernel_launch(void* const* d_in, const int* in_sizes, int n_in,
                              void* d_out, int out_size, void* d_ws, size_t ws_size,
                              hipStream_t stream) {
  const float* x   = (const float*)d_in[0];
  const float* ew1 = (const float*)d_in[1];
  const float* eb1 = (const float*)d_in[2];
  const float* ew2 = (const float*)d_in[3];
  const float* eb2 = (const float*)d_in[4];
  const float* ew3 = (const float*)d_in[5];
  const float* eb3 = (const float*)d_in[6];
  const float* dw1 = (const float*)d_in[7];
  const float* db1 = (const float*)d_in[8];
  const float* dw2 = (const float*)d_in[9];
  const float* db2 = (const float*)d_in[10];
  const float* dw3 = (const float*)d_in[11];
  const float* db3 = (const float*)d_in[12];
  const float* emb = (const float*)d_in[13];

  char* ws = (char*)d_ws;
  float* h1     = (float*)(ws);                    // N x 64   (reused as dec h2)
  float* h2     = (float*)(ws + 33554432ull);      // N x 128  (reused as dec h1)
  float* z_e    = (float*)(ws + 100663296ull);     // N x 256
  float* zsq    = (float*)(ws + 234881024ull);     // N
  float* esq    = (float*)(ws + 235405312ull);     // KE
  u64_t* keys   = (u64_t*)(ws + 235413504ull);     // N
  int* idx      = (int*)(ws + 236462080ull);       // N
  float* qparts = (float*)(ws + 236986368ull);     // N/4 = 32768
  float* rparts = (float*)(ws + 237117440ull);     // 1024*4 = 4096

  float* out = (float*)d_out;

  dim3 blk(256);

  // encoder: 512 -> 64 -> 128 -> 256  (all sequential-k fmac -> bit-exact z_e)
  gemm64<0><<<dim3(NROWS / 64, 1), blk, 0, stream>>>(x, ew1, eb1, h1, NROWS, 64, 512,
      nullptr);
  gemm128<0><<<dim3(NROWS / 128, 1), blk, 0, stream>>>(h1, ew2, eb2, h2,
      128, 64, nullptr, nullptr, nullptr, nullptr, nullptr, nullptr);
  gemm128<0><<<dim3(NROWS / 128, 2), blk, 0, stream>>>(h2, ew3, eb3, z_e,
      256, 128, nullptr, nullptr, nullptr, nullptr, nullptr, nullptr);

  rowsq<<<dim3(NROWS / 4), blk, 0, stream>>>(z_e, zsq, NROWS);
  rowsq<<<dim3(KE / 4), blk, 0, stream>>>(emb, esq, KE);
  init_keys<<<dim3(NROWS / 256), blk, 0, stream>>>(keys);

  // distances + argmin: 128x128 tile, bit-identical k-order dot products
  gemm128<3><<<dim3(NROWS / 128, KE / 128), blk, 0, stream>>>(z_e, emb, nullptr, nullptr,
      KE, 256, nullptr, nullptr, nullptr, zsq, esq, keys);

  gather_quant<<<dim3(NROWS / 4), blk, 0, stream>>>(keys, emb, z_e, out, idx, qparts);

  // decoder: 256 -> 128 -> 64 -> 512 (loss-only path, 2% threshold)
  gemm128<1><<<dim3(NROWS / 128, 1), blk, 0, stream>>>(emb, dw1, db1, h2,
      128, 256, idx, nullptr, nullptr, nullptr, nullptr, nullptr);
  gemm64<0><<<dim3(NROWS / 64, 1), blk, 0, stream>>>(h2, dw2, db2, h1, NROWS, 64, 128,
      nullptr);
  gemm128<2><<<dim3(NROWS / 128, 4), blk, 0, stream>>>(h1, dw3, db3, nullptr,
      512, 64, nullptr, x, rparts, nullptr, nullptr, nullptr);

  final_loss<<<dim3(1), blk, 0, stream>>>(qparts, NROWS / 4, rparts, 4096, out);
}